// Round 5
// baseline (309.071 us; speedup 1.0000x reference)
//
#include <hip/hip_runtime.h>

#define BB 8
#define CC_ALL 64
#define HH 192
#define WW 256
// tile
#define TH 8
#define TW 64
#define CCH 4          // channels per chunk
#define NCHUNK 16      // 64 / 4
#define LDW1 68        // padded stride for x1 tile rows (64 + 4)
#define LDW2 76        // padded stride for x2 halo rows (72 + 4)
#define THREADS 576    // 9 waves, wave w handles i = w - 4

typedef float f4 __attribute__((ext_vector_type(4)));
typedef float f8 __attribute__((ext_vector_type(8)));

// R2-R4 post-mortem: float acc[9][8] never got promoted out of its alloca
// (VGPR stuck at 84, ~470MB scratch evictions in WRITE_SIZE, VALUBusy 11%).
// Fix per rule #20: NO local arrays in the hot path. Nine named f8 vectors
// (mem2reg-trivial) + constant-mask shufflevector windows (free register
// renames) + elementwise FMA.
__global__ __launch_bounds__(THREADS) __attribute__((amdgpu_waves_per_eu(3, 3)))
void cost_volume_kernel(
    const float* __restrict__ x1, const float* __restrict__ x2,
    float* __restrict__ out)
{
    __shared__ __align__(16) float s1[2][CCH * TH * LDW1];        // x1 tile
    __shared__ __align__(16) float s2[2][CCH * (TH + 8) * LDW2];  // x2 halo

    const int tid  = threadIdx.x;
    const int wave = tid >> 6;        // 0..8  -> i = wave - 4
    const int lane = tid & 63;
    const int r    = lane >> 3;       // 0..7 tile row
    const int wcg  = lane & 7;        // 0..7 col group (8 w-pixels each)

    const int bid = blockIdx.x;
    const int b   = bid / 96;         // 24 h-tiles * 4 w-tiles = 96
    const int rem = bid % 96;
    const int th  = rem >> 2;
    const int tw  = rem & 3;
    const int h0  = th * TH;
    const int w0  = tw * TW;

    // ---------- staging descriptors (constant across chunks) ----------
    // x2 halo: 4ch x 16rows x 18 float4 = 1152 items; thread does q=tid, tid+576
    const int q0 = tid, q1 = tid + THREADS;
    const int ch_a = q0 / 288, ra = q0 % 288, hr_a = ra / 18, fc_a = ra % 18;
    const int ch_b = q1 / 288, rb = q1 % 288, hr_b = rb / 18, fc_b = rb % 18;
    const int hg_a = h0 + hr_a - 4, wg_a = w0 - 4 + fc_a * 4;
    const int hg_b = h0 + hr_b - 4, wg_b = w0 - 4 + fc_b * 4;
    const bool va = (hg_a >= 0 && hg_a < HH && wg_a >= 0 && wg_a < WW);
    const bool vb = (hg_b >= 0 && hg_b < HH && wg_b >= 0 && wg_b < WW);
    const int g2a = ((b * CC_ALL + ch_a) * HH + hg_a) * WW + wg_a;
    const int g2b = ((b * CC_ALL + ch_b) * HH + hg_b) * WW + wg_b;
    const int l2a = ch_a * ((TH + 8) * LDW2) + hr_a * LDW2 + fc_a * 4;
    const int l2b = ch_b * ((TH + 8) * LDW2) + hr_b * LDW2 + fc_b * 4;

    // x1 tile: 4ch x 8rows x 16 float4 = 512 items; threads 0..511
    const bool has1 = (tid < 512);
    const int ch1 = tid >> 7, r1i = tid & 127, hr1 = r1i >> 4, fc1 = r1i & 15;
    const int g1 = ((b * CC_ALL + ch1) * HH + (h0 + hr1)) * WW + w0 + fc1 * 4;
    const int l1 = ch1 * (TH * LDW1) + hr1 * LDW1 + fc1 * 4;

    const f4 z4 = {0.f, 0.f, 0.f, 0.f};
    f4 f2a = z4, f2b = z4, f1v = z4;

    auto load_chunk = [&](int n) {
        const int off = n * (CCH * HH * WW);
        f2a = va ? *(const f4*)(x2 + g2a + off) : z4;
        f2b = vb ? *(const f4*)(x2 + g2b + off) : z4;
        if (has1) f1v = *(const f4*)(x1 + g1 + off);
    };
    auto write_chunk = [&](int buf) {
        *(f4*)&s2[buf][l2a] = f2a;
        *(f4*)&s2[buf][l2b] = f2b;
        if (has1) *(f4*)&s1[buf][l1] = f1v;
    };

    f8 acc0 = {0,0,0,0,0,0,0,0}, acc1 = {0,0,0,0,0,0,0,0},
       acc2 = {0,0,0,0,0,0,0,0}, acc3 = {0,0,0,0,0,0,0,0},
       acc4 = {0,0,0,0,0,0,0,0}, acc5 = {0,0,0,0,0,0,0,0},
       acc6 = {0,0,0,0,0,0,0,0}, acc7 = {0,0,0,0,0,0,0,0},
       acc8 = {0,0,0,0,0,0,0,0};

    const int row2 = r + 8 - wave;   // = r + 4 - i, in [0,15]

    load_chunk(0);
    write_chunk(0);
    __syncthreads();

    for (int n = 0; n < NCHUNK; ++n) {
        if (n + 1 < NCHUNK) load_chunk(n + 1);
        const float* sb1 = s1[n & 1];
        const float* sb2 = s2[n & 1];
#pragma unroll
        for (int cc = 0; cc < CCH; ++cc) {
            const float* p1 = sb1 + cc * (TH * LDW1) + r * LDW1 + wcg * 8;
            const f4 a0 = *(const f4*)p1;
            const f4 a1 = *(const f4*)(p1 + 4);
            const float* p2 = sb2 + cc * ((TH + 8) * LDW2) + row2 * LDW2 + wcg * 8;
            const f4 b0 = *(const f4*)p2;
            const f4 b1 = *(const f4*)(p2 + 4);
            const f4 b2 = *(const f4*)(p2 + 8);
            const f4 b3 = *(const f4*)(p2 + 12);
            const f8 av  = __builtin_shufflevector(a0, a1, 0, 1, 2, 3, 4, 5, 6, 7);
            const f8 xlo = __builtin_shufflevector(b0, b1, 0, 1, 2, 3, 4, 5, 6, 7);
            const f8 xhi = __builtin_shufflevector(b2, b3, 0, 1, 2, 3, 4, 5, 6, 7);
            // out pixel p needs x[m], m = p + 8 - jj (x[0..7]=xlo, x[8..15]=xhi)
#define CV_STEP(JJ)                                                              \
            {                                                                    \
                const f8 xw = __builtin_shufflevector(                           \
                    xlo, xhi, 8 - (JJ), 9 - (JJ), 10 - (JJ), 11 - (JJ),          \
                    12 - (JJ), 13 - (JJ), 14 - (JJ), 15 - (JJ));                 \
                acc##JJ = __builtin_elementwise_fma(av, xw, acc##JJ);            \
            }
            CV_STEP(0) CV_STEP(1) CV_STEP(2) CV_STEP(3) CV_STEP(4)
            CV_STEP(5) CV_STEP(6) CV_STEP(7) CV_STEP(8)
#undef CV_STEP
        }
        __syncthreads();
        if (n + 1 < NCHUNK) write_chunk((n + 1) & 1);
        __syncthreads();
    }

    // ---------- epilogue: scale and store ----------
    const float scale = 1.0f / 81.0f;
    const int hout = h0 + r;
    const int wout = w0 + wcg * 8;
    // k = (9*i + j) mod 81, i = wave-4, j = jj-4  ->  (9*wave + jj + 41) mod 81
#define CV_OUT(JJ)                                                               \
    {                                                                            \
        const int k = (9 * wave + (JJ) + 41) % 81;                               \
        float* po = out + ((b * 81 + k) * HH + hout) * WW + wout;                \
        const f8 o = acc##JJ * scale;                                            \
        *(f8*)po = o;                                                            \
    }
    CV_OUT(0) CV_OUT(1) CV_OUT(2) CV_OUT(3) CV_OUT(4)
    CV_OUT(5) CV_OUT(6) CV_OUT(7) CV_OUT(8)
#undef CV_OUT
}

extern "C" void kernel_launch(void* const* d_in, const int* in_sizes, int n_in,
                              void* d_out, int out_size, void* d_ws, size_t ws_size,
                              hipStream_t stream) {
    const float* x1 = (const float*)d_in[0];
    const float* x2 = (const float*)d_in[1];
    float* out = (float*)d_out;
    dim3 grid(BB * 24 * 4);   // 8 batches * 24 h-tiles * 4 w-tiles = 768
    dim3 block(THREADS);
    hipLaunchKernelGGL(cost_volume_kernel, grid, block, 0, stream, x1, x2, out);
}

// Round 6
// 120.657 us; speedup vs baseline: 2.5616x; 2.5616x over previous
//
#include <hip/hip_runtime.h>

#define HH 192
#define WW 256
#define TH 8
#define TW 32
#define CCH 4            // channels per chunk
#define NCHUNK 16        // 64 / 4
#define THREADS 576      // 9 waves; wave w handles i = w - 4
#define CHSTEP (CCH * HH * WW)  // float advance per channel-chunk

typedef float f4 __attribute__((ext_vector_type(4)));

// async global->LDS, 16B per lane, dest = wave-uniform base + lane*16
#define GLL(gp, lp) __builtin_amdgcn_global_load_lds(                        \
    (const __attribute__((address_space(1))) unsigned int*)(gp),            \
    (__attribute__((address_space(3))) unsigned int*)(lp), 16, 0, 0)

// smem layout (floats, linear, unpadded — required by global_load_lds):
//   s1[buf][ch][row][col32] at  buf*1024 + ch*256 + row*32 + col
//   s2[buf][ch][row][col40] at  2048 + buf*2560 + ch*640 + row*40 + col
// total 7168 floats = 28 KiB
__global__ __launch_bounds__(THREADS) void cost_volume_kernel(
    const float* __restrict__ x1, const float* __restrict__ x2,
    float* __restrict__ out)
{
    __shared__ __align__(16) float smem[7168];

    const int tid  = threadIdx.x;
    const int wave = tid >> 6;      // 0..8 -> i = wave - 4
    const int lane = tid & 63;
    const int r    = lane >> 3;     // 0..7 tile row
    const int wcg  = lane & 7;      // 0..7 col group (4 px each)

    const int bid = blockIdx.x;
    const int b   = bid / 192;      // 24 h-tiles * 8 w-tiles
    const int rem = bid % 192;
    const int h0  = (rem >> 3) * TH;
    const int w0  = (rem & 7) * TW;

    // ---- staging descriptors (16B units; chunk-invariant) ----
    // x2 halo [4][16][40] = 640 units; call A: unit = tid (waves 0..8),
    // call B: unit = 576+lane (wave 0 only)
    const int u2a = tid;
    const int ch2a = u2a / 160, r2a = (u2a % 160) / 10, c2a = (u2a % 10) * 4;
    const int hg2a = h0 - 4 + r2a, wg2a = w0 - 4 + c2a;
    const bool v2a = (hg2a >= 0) & (hg2a < HH) & (wg2a >= 0) & (wg2a <= WW - 4);
    const long off2a = ((long)(b * 64 + ch2a) * HH + hg2a) * WW + wg2a;

    const int u2b = 576 + lane;
    const int ch2b = u2b / 160, r2b = (u2b % 160) / 10, c2b = (u2b % 10) * 4;
    const int hg2b = h0 - 4 + r2b, wg2b = w0 - 4 + c2b;
    const bool v2b = (wave == 0) & (hg2b >= 0) & (hg2b < HH) &
                     (wg2b >= 0) & (wg2b <= WW - 4);
    const long off2b = ((long)(b * 64 + ch2b) * HH + hg2b) * WW + wg2b;

    // x1 tile [4][8][32] = 256 units; waves 1..4, unit = 64*(wave-1)+lane
    const bool hx1 = (wave >= 1) & (wave <= 4);
    const int u1 = (64 * (wave - 1) + lane) & 255;
    const int ch1 = u1 >> 6, r1 = (u1 & 63) >> 3, c1 = (u1 & 7) * 4;
    const long off1 = ((long)(b * 64 + ch1) * HH + (h0 + r1)) * WW + (w0 + c1);

    auto issue = [&](int nb, int n) {  // stage chunk n into buffer nb
        const long cofs = (long)n * CHSTEP;
        float* const l2a = smem + 2048 + nb * 2560 + 256 * wave;     // wave-uniform
        float* const l2b = smem + 2048 + nb * 2560 + 2304;
        float* const l1  = smem + nb * 1024 + 256 * (wave - 1);
        if (v2a) GLL(x2 + off2a + cofs, l2a);
        if (v2b) GLL(x2 + off2b + cofs, l2b);
        if (hx1) GLL(x1 + off1 + cofs, l1);
    };

    // ---- pre-zero LDS: OOB halo slots are never written by masked lanes ----
    const f4 z4 = {0.f, 0.f, 0.f, 0.f};
    for (int z = tid; z < 7168 / 4; z += THREADS) ((f4*)smem)[z] = z4;
    __syncthreads();

    issue(0, 0);
    __syncthreads();   // __syncthreads drains vmcnt(0) before s_barrier

    f4 acc0 = z4, acc1 = z4, acc2 = z4, acc3 = z4, acc4 = z4,
       acc5 = z4, acc6 = z4, acc7 = z4, acc8 = z4;

    const int row2 = r + 8 - wave;   // x2 halo row, in [0,15]

    for (int n = 0; n < NCHUNK; ++n) {
        if (n + 1 < NCHUNK) issue((n + 1) & 1, n + 1);
        const float* sb1 = smem + (n & 1) * 1024 + r * 32 + wcg * 4;
        const float* sb2 = smem + 2048 + (n & 1) * 2560 + row2 * 40 + wcg * 4;
#pragma unroll
        for (int cc = 0; cc < CCH; ++cc) {
            const f4 av  = *(const f4*)(sb1 + cc * 256);
            const f4 xv0 = *(const f4*)(sb2 + cc * 640);
            const f4 xv1 = *(const f4*)(sb2 + cc * 640 + 4);
            const f4 xv2 = *(const f4*)(sb2 + cc * 640 + 8);
            // out px p needs halo col wcg*4 + p + 8 - jj  (p=0..3)
            const f4 w8 = xv0;
            const f4 w7 = __builtin_shufflevector(xv0, xv1, 1, 2, 3, 4);
            const f4 w6 = __builtin_shufflevector(xv0, xv1, 2, 3, 4, 5);
            const f4 w5 = __builtin_shufflevector(xv0, xv1, 3, 4, 5, 6);
            const f4 w4 = xv1;
            const f4 w3 = __builtin_shufflevector(xv1, xv2, 1, 2, 3, 4);
            const f4 w2 = __builtin_shufflevector(xv1, xv2, 2, 3, 4, 5);
            const f4 w1 = __builtin_shufflevector(xv1, xv2, 3, 4, 5, 6);
            const f4 w0 = xv2;
            acc0 = __builtin_elementwise_fma(av, w0, acc0);
            acc1 = __builtin_elementwise_fma(av, w1, acc1);
            acc2 = __builtin_elementwise_fma(av, w2, acc2);
            acc3 = __builtin_elementwise_fma(av, w3, acc3);
            acc4 = __builtin_elementwise_fma(av, w4, acc4);
            acc5 = __builtin_elementwise_fma(av, w5, acc5);
            acc6 = __builtin_elementwise_fma(av, w6, acc6);
            acc7 = __builtin_elementwise_fma(av, w7, acc7);
            acc8 = __builtin_elementwise_fma(av, w8, acc8);
        }
        __syncthreads();
    }

    // ---- epilogue ----
    const float scale = 1.0f / 81.0f;
    const int hout = h0 + r;
    const int wout = w0 + wcg * 4;
    // k = (9*i + j) mod 81 = (9*wave + jj + 41) mod 81
#define CV_OUT(JJ)                                                           \
    {                                                                        \
        const int k = (9 * wave + (JJ) + 41) % 81;                           \
        float* po = out + (((long)b * 81 + k) * HH + hout) * WW + wout;      \
        *(f4*)po = acc##JJ * scale;                                          \
    }
    CV_OUT(0) CV_OUT(1) CV_OUT(2) CV_OUT(3) CV_OUT(4)
    CV_OUT(5) CV_OUT(6) CV_OUT(7) CV_OUT(8)
#undef CV_OUT
}

extern "C" void kernel_launch(void* const* d_in, const int* in_sizes, int n_in,
                              void* d_out, int out_size, void* d_ws, size_t ws_size,
                              hipStream_t stream) {
    const float* x1 = (const float*)d_in[0];
    const float* x2 = (const float*)d_in[1];
    float* out = (float*)d_out;
    dim3 grid(8 * 24 * 8);   // 1536 blocks: 8 batches * 24 h-tiles * 8 w-tiles
    dim3 block(THREADS);
    hipLaunchKernelGGL(cost_volume_kernel, grid, block, 0, stream, x1, x2, out);
}